// Round 1
// baseline (168.827 us; speedup 1.0000x reference)
//
#include <hip/hip_runtime.h>
#include <hip/hip_bf16.h>

// Problem: BS=64, S=1024, F=3, D=128, M=4.
// Dead-code analysis: sum(softmax(x),axis)==1 => attention branch, sh*/sg*
// branch, query, n are all unused. Live compute:
//   h1[m]  = relu(xf(64x3072) @ ah1_w[m](3072x1024) + ah1_b[m])
//   r[:,m] = relu(h1[m] @ ah2_w[m](1024x128) + ah2_b[m])
//   out    = sigmoid(relu(relu(r@f1+b)@f2+b)@f3+b)

#define K1   3072
#define N1   1024
#define KSPL 4
#define KRNG 768      // K1/KSPL
#define BK   32
#define NIT  24       // KRNG/BK
#define BN   32

typedef short bf16x8 __attribute__((ext_vector_type(8)));
typedef float f32x4  __attribute__((ext_vector_type(4)));
typedef unsigned short ushort4v __attribute__((ext_vector_type(4)));

__device__ __forceinline__ unsigned short f2b(float f) {
  unsigned int u = __float_as_uint(f);
  unsigned int r = (u + 0x7FFFu + ((u >> 16) & 1u)) >> 16;   // RNE
  return (unsigned short)r;
}
__device__ __forceinline__ float relu(float v) { return v > 0.f ? v : 0.f; }

// ---------------- kernel 1: xf (f32) -> bf16 ----------------
__global__ void k_convert_x(const float* __restrict__ x, unsigned short* __restrict__ A) {
  int i = (blockIdx.x * 256 + threadIdx.x) * 4;     // 196608 total
  float4 v = *reinterpret_cast<const float4*>(x + i);
  ushort4v o;
  o.x = f2b(v.x); o.y = f2b(v.y); o.z = f2b(v.z); o.w = f2b(v.w);
  *reinterpret_cast<ushort4v*>(A + i) = o;
}

// ---------------- kernel 2: big GEMM, bf16 MFMA, split-K ----------------
// LDS holds B tile transposed (col-major in k) with XOR chunk swizzle so the
// B fragment is one 16B-aligned ds_read_b128 and banks are spread.
__device__ __forceinline__ int bchunk(int c, int q) {
  return c * 4 + (q ^ (c & 3) ^ ((c >> 2) & 3));
}

__global__ __launch_bounds__(256, 2) void k_gemm1(
    const unsigned short* __restrict__ A,   // [64][3072] bf16
    const float* __restrict__ W,            // ah1_w [4][3072][1024]
    float* __restrict__ part)               // [KSPL][4][64][1024]
{
  __shared__ __align__(16) unsigned short Bt[BN * BK];  // 2KB, chunk-addressed

  const int nt = blockIdx.x, ks = blockIdx.y, h = blockIdx.z;
  const int tid = threadIdx.x;
  const float* Wg = W + (size_t)h * K1 * N1 + nt * BN;
  const int kbase = ks * KRNG;

  const int skr = tid >> 3;           // staging local k-row 0..31
  const int sc4 = (tid & 7) * 4;      // staging col quad
  const int w = tid >> 6, lane = tid & 63, lr = lane & 15, lkg = lane >> 4;

  const unsigned short* Ap = A + (size_t)(16 * w + lr) * K1 + kbase + lkg * 8;

  f32x4 acc0 = {0.f, 0.f, 0.f, 0.f}, acc1 = {0.f, 0.f, 0.f, 0.f};

  // prefetch tile 0
  float4 bpre = *reinterpret_cast<const float4*>(Wg + (size_t)(kbase + skr) * N1 + sc4);
  bf16x8 apre = *reinterpret_cast<const bf16x8*>(Ap);

  for (int it = 0; it < NIT; ++it) {
    {  // stage current B tile into LDS (f32 -> bf16, transposed + swizzled)
      const int q = skr >> 3, klo = skr & 7;
      Bt[bchunk(sc4 + 0, q) * 8 + klo] = f2b(bpre.x);
      Bt[bchunk(sc4 + 1, q) * 8 + klo] = f2b(bpre.y);
      Bt[bchunk(sc4 + 2, q) * 8 + klo] = f2b(bpre.z);
      Bt[bchunk(sc4 + 3, q) * 8 + klo] = f2b(bpre.w);
    }
    __syncthreads();
    bf16x8 af  = apre;
    bf16x8 bf0 = *reinterpret_cast<const bf16x8*>(&Bt[bchunk(lr,      lkg) * 8]);
    bf16x8 bf1 = *reinterpret_cast<const bf16x8*>(&Bt[bchunk(16 + lr, lkg) * 8]);
    if (it + 1 < NIT) {  // issue next-tile loads before the MFMAs
      const int kn = kbase + (it + 1) * BK;
      bpre = *reinterpret_cast<const float4*>(Wg + (size_t)(kn + skr) * N1 + sc4);
      apre = *reinterpret_cast<const bf16x8*>(Ap + (it + 1) * BK);
    }
    acc0 = __builtin_amdgcn_mfma_f32_16x16x32_bf16(af, bf0, acc0, 0, 0, 0);
    acc1 = __builtin_amdgcn_mfma_f32_16x16x32_bf16(af, bf1, acc1, 0, 0, 0);
    __syncthreads();
  }

  // store partial C. D layout: col = lane&15, row = (lane>>4)*4 + i
  float* P = part + ((size_t)ks * 4 + h) * (64 * N1)
                  + (size_t)(16 * w + lkg * 4) * N1 + nt * BN + lr;
#pragma unroll
  for (int i = 0; i < 4; ++i) {
    P[(size_t)i * N1]      = acc0[i];
    P[(size_t)i * N1 + 16] = acc1[i];
  }
}

// ---------------- kernel 3: split-K reduce + bias + relu ----------------
__global__ void k_reduce_relu(const float* __restrict__ part,
                              const float* __restrict__ b1,   // [4][1024]
                              float* __restrict__ h1)         // [4][64][1024]
{
  int i = (blockIdx.x * 256 + threadIdx.x) * 4;  // over 262144
  float4 s0 = *reinterpret_cast<const float4*>(part + i);
  float4 s1 = *reinterpret_cast<const float4*>(part + i + 262144);
  float4 s2 = *reinterpret_cast<const float4*>(part + i + 524288);
  float4 s3 = *reinterpret_cast<const float4*>(part + i + 786432);
  float4 b  = *reinterpret_cast<const float4*>(b1 + (i >> 16) * 1024 + (i & 1023));
  float4 o;
  o.x = relu(s0.x + s1.x + s2.x + s3.x + b.x);
  o.y = relu(s0.y + s1.y + s2.y + s3.y + b.y);
  o.z = relu(s0.z + s1.z + s2.z + s3.z + b.z);
  o.w = relu(s0.w + s1.w + s2.w + s3.w + b.w);
  *reinterpret_cast<float4*>(h1 + i) = o;
}

// ---------------- kernel 4: per-head GEMM2 (f32 vector) ----------------
__global__ __launch_bounds__(512) void k_gemm2(
    const float* __restrict__ h1,   // [4][64][1024]
    const float* __restrict__ W2,   // ah2_w [4][1024][128]
    float* __restrict__ r)          // [64][512] raw (bias+relu in k_final)
{
  const int b = blockIdx.x, h = blockIdx.y;
  const int t = threadIdx.x;
  const int d = t & 127, ksl = t >> 7;             // 4-way local K split
  const float* hr = h1 + ((size_t)h * 64 + b) * 1024 + ksl * 256;
  const float* Wp = W2 + (size_t)h * 1024 * 128 + (size_t)ksl * 256 * 128 + d;
  float a0 = 0.f, a1 = 0.f, a2 = 0.f, a3 = 0.f;
#pragma unroll 4
  for (int k = 0; k < 256; k += 4) {
    a0 += hr[k + 0] * Wp[(size_t)(k + 0) * 128];
    a1 += hr[k + 1] * Wp[(size_t)(k + 1) * 128];
    a2 += hr[k + 2] * Wp[(size_t)(k + 2) * 128];
    a3 += hr[k + 3] * Wp[(size_t)(k + 3) * 128];
  }
  __shared__ float red[4][128];
  red[ksl][d] = a0 + a1 + a2 + a3;
  __syncthreads();
  if (t < 128) {
    float s = red[0][t] + red[1][t] + red[2][t] + red[3][t];
    r[(size_t)b * 512 + h * 128 + t] = s;
  }
}

// ---------------- kernel 5: fused final MLP + sigmoid ----------------
__global__ __launch_bounds__(512) void k_final(
    const float* __restrict__ r,    // [64][512] raw
    const float* __restrict__ b2,   // ah2_b flat [512]
    const float* __restrict__ f1w, const float* __restrict__ f1b,
    const float* __restrict__ f2w, const float* __restrict__ f2b,
    const float* __restrict__ f3w, const float* __restrict__ f3b,
    float* __restrict__ out)
{
  const int b = blockIdx.x, t = threadIdx.x;
  __shared__ float rr[512];
  __shared__ float y1p[2][256];
  __shared__ float y1[256];
  __shared__ float y2p[4][64];
  __shared__ float y2[64];

  rr[t] = relu(r[(size_t)b * 512 + t] + b2[t]);
  __syncthreads();

  {  // y1 = relu(rr @ f1w + f1b), K=512 split over 2
    const int j = t & 255, kh = t >> 8;
    const float* W = f1w + (size_t)kh * 256 * 256 + j;
    const float* rv = rr + kh * 256;
    float a0 = 0.f, a1 = 0.f, a2 = 0.f, a3 = 0.f;
#pragma unroll 4
    for (int k = 0; k < 256; k += 4) {
      a0 += rv[k + 0] * W[(size_t)(k + 0) * 256];
      a1 += rv[k + 1] * W[(size_t)(k + 1) * 256];
      a2 += rv[k + 2] * W[(size_t)(k + 2) * 256];
      a3 += rv[k + 3] * W[(size_t)(k + 3) * 256];
    }
    y1p[kh][j] = a0 + a1 + a2 + a3;
  }
  __syncthreads();
  if (t < 256) y1[t] = relu(y1p[0][t] + y1p[1][t] + f1b[t]);
  __syncthreads();

  if (t < 256) {  // y2 = relu(y1 @ f2w + f2b), K=256 split over 4
    const int j = t & 63, kh = t >> 6;
    const float* W = f2w + (size_t)kh * 64 * 64 + j;
    const float* yv = y1 + kh * 64;
    float a = 0.f;
#pragma unroll 4
    for (int k = 0; k < 64; ++k) a += yv[k] * W[(size_t)k * 64];
    y2p[kh][j] = a;
  }
  __syncthreads();
  if (t < 64) y2[t] = relu(y2p[0][t] + y2p[1][t] + y2p[2][t] + y2p[3][t] + f2b[t]);
  __syncthreads();

  if (t == 0) {
    float s = f3b[0];
#pragma unroll 8
    for (int k = 0; k < 64; ++k) s += y2[k] * f3w[k];
    out[b] = 1.f / (1.f + expf(-s));
  }
}

extern "C" void kernel_launch(void* const* d_in, const int* in_sizes, int n_in,
                              void* d_out, int out_size, void* d_ws, size_t ws_size,
                              hipStream_t stream) {
  (void)in_sizes; (void)n_in; (void)out_size; (void)ws_size;
  const float* x     = (const float*)d_in[0];
  const float* ah1_w = (const float*)d_in[12];
  const float* ah1_b = (const float*)d_in[13];
  const float* ah2_w = (const float*)d_in[14];
  const float* ah2_b = (const float*)d_in[15];
  const float* f1w   = (const float*)d_in[16];
  const float* f1b   = (const float*)d_in[17];
  const float* f2w   = (const float*)d_in[18];
  const float* f2b   = (const float*)d_in[19];
  const float* f3w   = (const float*)d_in[20];
  const float* f3b   = (const float*)d_in[21];
  float* out = (float*)d_out;

  char* ws = (char*)d_ws;
  unsigned short* A = (unsigned short*)ws;                  // 384 KB bf16 xf
  float* part = (float*)(ws + 524288);                      // 4 MB partials
  float* h1   = (float*)(ws + 524288 + 4194304);            // 1 MB
  float* r    = (float*)(ws + 524288 + 4194304 + 1048576);  // 128 KB

  k_convert_x<<<192, 256, 0, stream>>>(x, A);
  k_gemm1<<<dim3(32, KSPL, 4), 256, 0, stream>>>(A, ah1_w, part);
  k_reduce_relu<<<256, 256, 0, stream>>>(part, ah1_b, h1);
  k_gemm2<<<dim3(64, 4), 512, 0, stream>>>(h1, ah2_w, r);
  k_final<<<64, 512, 0, stream>>>(r, ah2_b, f1w, f1b, f2w, f2b, f3w, f3b, out);
}